// Round 6
// baseline (1670.707 us; speedup 1.0000x reference)
//
#include <hip/hip_runtime.h>

typedef float f32x4  __attribute__((ext_vector_type(4)));
typedef float f32x16 __attribute__((ext_vector_type(16)));
typedef int   i32x4  __attribute__((ext_vector_type(4)));
typedef int   i32x8  __attribute__((ext_vector_type(8)));

#define AS1 __attribute__((address_space(1)))
#define AS3 __attribute__((address_space(3)))

// ---------------------------------------------------------------------------
// Kernel 1 (R1, proven): per-token quant of x -> fp8 e4m3 + scale
// ---------------------------------------------------------------------------
__global__ __launch_bounds__(256) void quant_x_fp8_kernel(
    const float* __restrict__ x, unsigned char* __restrict__ x8,
    float* __restrict__ xs, int K) {
  int m = blockIdx.x;
  int t = threadIdx.x;
  const f32x4* src = (const f32x4*)(x + (size_t)m * K + t * 16);
  f32x4 v[4];
  float am = 0.0f;
#pragma unroll
  for (int i = 0; i < 4; ++i) {
    v[i] = src[i];
#pragma unroll
    for (int j = 0; j < 4; ++j) am = fmaxf(am, __builtin_fabsf(v[i][j]));
  }
#pragma unroll
  for (int off = 32; off >= 1; off >>= 1)
    am = fmaxf(am, __shfl_xor(am, off, 64));
  __shared__ float red[4];
  int wv = t >> 6, lane = t & 63;
  if (lane == 0) red[wv] = am;
  __syncthreads();
  am = fmaxf(fmaxf(red[0], red[1]), fmaxf(red[2], red[3]));
  am = fmaxf(am, 1e-12f);
  float sc = am / 448.0f;
  if (t == 0) xs[m] = sc;
  i32x4 out;
#pragma unroll
  for (int i = 0; i < 4; ++i) {
    float q0 = v[i][0] / sc, q1 = v[i][1] / sc;
    float q2 = v[i][2] / sc, q3 = v[i][3] / sc;
    int p = __builtin_amdgcn_cvt_pk_fp8_f32(q0, q1, 0, false);
    p = __builtin_amdgcn_cvt_pk_fp8_f32(q2, q3, p, true);
    out[i] = p;
  }
  *(i32x4*)(x8 + (size_t)m * K + t * 16) = out;
}

// ---------------------------------------------------------------------------
// Kernel 2 (R1, proven): weight f32 (fp8-representable) -> fp8 bytes
// ---------------------------------------------------------------------------
__global__ __launch_bounds__(256) void quant_w_fp8_kernel(
    const float* __restrict__ w, unsigned char* __restrict__ w8) {
  size_t idx = (size_t)blockIdx.x * 256 + threadIdx.x;
  const f32x4* src = (const f32x4*)w + idx * 4;
  i32x4 out;
#pragma unroll
  for (int i = 0; i < 4; ++i) {
    f32x4 v = src[i];
    int p = __builtin_amdgcn_cvt_pk_fp8_f32(v[0], v[1], 0, false);
    p = __builtin_amdgcn_cvt_pk_fp8_f32(v[2], v[3], p, true);
    out[i] = p;
  }
  ((i32x4*)w8)[idx] = out;
}

// ---------------------------------------------------------------------------
// Kernel 3: MX-fp8 GEMM. R18 = register double-buffered fragments.
// R17 post-mortem: removing barriers gave 185->181us only; MfmaUtil 33,
// VALUBusy 28. Model that fits: per-tile ~3400cy = LDS reads + MFMA + VALU
// run SERIALLY -- every wave does {16 ds_reads -> lgkm wait -> MFMA}, and
// both waves/SIMD are phase-locked (same program, same barrier), so LDS
// and MFMA pipes alternate idle. Fix: read tile T+1's fragments into a
// SECOND 64-VGPR frag set during tile T's MFMAs (MFMA never lgkm-waits;
// LDS services next-tile reads under the MFMA pipe). Register budget ok:
// R17 used 88 of 256; frags 2x64 + acc 64 + addr ~= 225.
// Geometry (R12-proven): block 256(M)x128(N), K-tile 128 (= scale block),
// 8 waves 4(wr)x2(wc), wave 64x64 -> acc[2][2] f32x16 = 64 VGPR.
// Buffers: 3 LDS bufs x 48KB = 147456 (buf k: A@k*49152, B@+32768).
// Body T: stage tile T+3 -> buf(T%3); read frags of T+1 from buf((T+1)%3)
// into the alternate set; MFMA tile T from current set; lgkmcnt(0) [drain
// this body's reads -> cross-wave WAR safety at the barrier]; vmcnt(6);
// barrier. Buf/set assignment STATIC via 6-body groups (lcm(3,2)) -- no
// rotating registers (R16 spill lesson).
// vmcnt ledger: end of body T outstanding = STG(T+2) [issued T-1] +
// STG(T+3) [issued T] = 12; vmcnt(6) retires STG(T+2), read in body T+1 ok.
// Prologue stages tiles 0,1,2; vmcnt(6) retires 0,1; reads tile0 frags;
// lgkm(0)+barrier (all waves' tile0 reads drained before body0 overwrites
// buf0 with tile3). Tail: body 29 vmcnt(0) (retire STG(31) before body 30
// reads it), bodies 30/31 no stage, body 31 no read.
// WAR: STG(T+3)->buf(T%3): that buf was read in body T-1, drained by the
// lgkmcnt(0) before body T-1's closing barrier (all waves) -> race-free.
// Swizzle (validated): 16B slot s at row r stored s^(r&7); inverse applied
// on global source (rule #21).
// ---------------------------------------------------------------------------
__global__ __launch_bounds__(512, 1) void gemm_mxfp8_kernel(
    const unsigned char* __restrict__ A8,   // [M][K] fp8
    const unsigned char* __restrict__ W8,   // [N][K] fp8
    const float* __restrict__ xs,           // [M]
    const float* __restrict__ wsinv,        // [N/128][K/128]
    float* __restrict__ Y,                  // [M][N] f32
    int M, int N, int K) {
  const int KB = K >> 7;  // K/128 tiles (32); schedule assumes KB == 32

  int bid = blockIdx.x, nwg = gridDim.x;
  int wg = (bid & 7) * (nwg >> 3) + (bid >> 3);
  int mt = M >> 8;                  // 16
  int bm = wg & (mt - 1);
  int bn = wg / mt;
  int m0 = bm << 8, n0 = bn << 7;   // 256 x 128 tile

  __shared__ __align__(16) char lds[147456];  // 3 x 48KB

  const int tid = threadIdx.x, wv = tid >> 6, lane = tid & 63;
  const int wr = wv >> 1, wc = wv & 1;          // 4 x 2 wave grid
  const int l31 = lane & 31, hi2 = lane >> 5;
  const int salt = l31 & 7;

  // per-lane slot offsets (validated swizzle)
  const int sL0 = ((hi2 * 2 + 0) ^ salt) << 4;       // ks=0, k-low 16B
  const int sH0 = ((hi2 * 2 + 1) ^ salt) << 4;       // ks=0, k-high
  const int sL1 = ((4 + hi2 * 2 + 0) ^ salt) << 4;   // ks=1
  const int sH1 = ((4 + hi2 * 2 + 1) ^ salt) << 4;

  // per-lane anchors (buf base added as compile-time literal per body)
  const int aRow = (wr * 64 + l31) * 128;
  const int bRow = (wc * 64 + l31) * 128;
  const int aL0 = aRow + sL0, aH0 = aRow + sH0;
  const int aL1 = aRow + sL1, aH1 = aRow + sH1;
  const int bL0 = bRow + sL0, bH0 = bRow + sH0;
  const int bL1 = bRow + sL1, bH1 = bRow + sH1;

  // staging: dest = region + sweep*8192 + tid*16 (linear, 64 rows/sweep);
  // source row = sweep*64 + (tid>>3); col pre-swizzled (involution).
  const int stgD = tid << 4;
  const int rIdx = tid >> 3;
  const int cSrc = ((tid & 7) ^ ((tid >> 3) & 7)) << 4;
  const size_t rowB = (size_t)K;  // fp8: 1 byte/elem
  const size_t g64 = 64 * rowB;
  const char* pA = (const char*)A8 + (size_t)(m0 + rIdx) * rowB + cSrc;
  const char* pB = (const char*)W8 + (size_t)(n0 + rIdx) * rowB + cSrc;

  const float* wsv = wsinv + (size_t)bn * KB;  // block-uniform scale row

  f32x16 acc[2][2];
#pragma unroll
  for (int i = 0; i < 2; ++i)
#pragma unroll
    for (int j = 0; j < 2; ++j) acc[i][j] = (f32x16)0.0f;

  // two fragment sets (E/O), statically addressed: [mj][ks] / [nj][ks]
  i32x8 afE[2][2], bfE[2][2], afO[2][2], bfO[2][2];

#define GL(SRC, DST)                                                           \
  __builtin_amdgcn_global_load_lds((const AS1 void*)(SRC), (AS3 void*)(DST),   \
                                   16, 0, 0)
#define STG_A(COND, SB, SRC)                                                   \
  if (COND) {                                                                  \
    const char* s_ = (SRC);                                                    \
    char* d_ = lds + (SB) + stgD;                                              \
    GL(s_, d_);                                                                \
    GL(s_ + g64, d_ + 8192);                                                   \
    GL(s_ + 2 * g64, d_ + 16384);                                              \
    GL(s_ + 3 * g64, d_ + 24576);                                              \
  }
#define STG_B(COND, SB, SRC)                                                   \
  if (COND) {                                                                  \
    const char* s_ = (SRC);                                                    \
    char* d_ = lds + (SB) + stgD;                                              \
    GL(s_, d_);                                                                \
    GL(s_ + g64, d_ + 8192);                                                   \
  }

// full frag set for one tile from buf at literal base BR: 16 ds_read_b128
#define RD_FRAGS(BR, AF, BF)                                                   \
  {                                                                            \
    _Pragma("unroll") for (int mj = 0; mj < 2; ++mj) {                         \
      const char* p_ = lds + (BR) + mj * 4096;                                 \
      i32x4 lo0 = *(const i32x4*)(p_ + aL0);                                   \
      i32x4 hi0 = *(const i32x4*)(p_ + aH0);                                   \
      i32x4 lo1 = *(const i32x4*)(p_ + aL1);                                   \
      i32x4 hi1 = *(const i32x4*)(p_ + aH1);                                   \
      AF[mj][0] = __builtin_shufflevector(lo0, hi0, 0, 1, 2, 3, 4, 5, 6, 7);   \
      AF[mj][1] = __builtin_shufflevector(lo1, hi1, 0, 1, 2, 3, 4, 5, 6, 7);   \
    }                                                                          \
    _Pragma("unroll") for (int nj = 0; nj < 2; ++nj) {                         \
      const char* p_ = lds + (BR) + 32768 + nj * 4096;                         \
      i32x4 lo0 = *(const i32x4*)(p_ + bL0);                                   \
      i32x4 hi0 = *(const i32x4*)(p_ + bH0);                                   \
      i32x4 lo1 = *(const i32x4*)(p_ + bL1);                                   \
      i32x4 hi1 = *(const i32x4*)(p_ + bH1);                                   \
      BF[nj][0] = __builtin_shufflevector(lo0, hi0, 0, 1, 2, 3, 4, 5, 6, 7);   \
      BF[nj][1] = __builtin_shufflevector(lo1, hi1, 0, 1, 2, 3, 4, 5, 6, 7);   \
    }                                                                          \
  }

// 8 MFMA (2mj x 2nj x ks-chain) + fold by SV into acc
#define MFMA_ALL(AF, BF, SV)                                                   \
  _Pragma("unroll") for (int mj = 0; mj < 2; ++mj)                             \
  _Pragma("unroll") for (int nj = 0; nj < 2; ++nj) {                           \
    f32x16 t_ = __builtin_amdgcn_mfma_scale_f32_32x32x64_f8f6f4(               \
        AF[mj][0], BF[nj][0], (f32x16)0.0f, 0, 0, 0, 0x7f7f7f7f, 0,            \
        0x7f7f7f7f);                                                           \
    t_ = __builtin_amdgcn_mfma_scale_f32_32x32x64_f8f6f4(                      \
        AF[mj][1], BF[nj][1], t_, 0, 0, 0, 0x7f7f7f7f, 0, 0x7f7f7f7f);         \
    _Pragma("unroll") for (int q = 0; q < 16; ++q)                             \
        acc[mj][nj][q] = __builtin_fmaf(SV, t_[q], acc[mj][nj][q]);            \
  }

// body T: stage T+3 -> BS; read frags T+1 from BR into (AFr,BFr);
// MFMA tile T from (AFm,BFm); lgkm drain; vmcnt; barrier.
#define BODY(T, BS, BR, AFm, BFm, AFr, BFr, G, DO_RD, VM)                      \
  {                                                                            \
    float s_ = wsv[(T)];                                                       \
    STG_A(G, (BS), pAs);                                                       \
    STG_B(G, (BS) + 32768, pBs);                                               \
    if (DO_RD) RD_FRAGS((BR), AFr, BFr);                                       \
    __builtin_amdgcn_s_setprio(1);                                             \
    MFMA_ALL(AFm, BFm, s_);                                                    \
    __builtin_amdgcn_s_setprio(0);                                             \
    asm volatile("s_waitcnt lgkmcnt(0)" ::: "memory");                         \
    asm volatile("s_waitcnt " VM ::: "memory");                                \
    __builtin_amdgcn_s_barrier();                                              \
    pAs += 128;                                                                \
    pBs += 128;                                                                \
  }

  // prologue: stage tiles 0,1,2 into bufs 0,1,2 (18 gloads);
  // vmcnt(6) retires tiles 0,1 (12 oldest), leaves tile2's 6; barrier;
  // read tile0 frags into set E; lgkm(0)+barrier so every wave's tile0
  // reads are drained before body0 overwrites buf0 with tile3.
  STG_A(true, 0, pA);
  STG_B(true, 32768, pB);
  STG_A(true, 49152, pA + 128);
  STG_B(true, 81920, pB + 128);
  STG_A(true, 98304, pA + 256);
  STG_B(true, 131072, pB + 256);
  asm volatile("s_waitcnt vmcnt(6)" ::: "memory");
  __builtin_amdgcn_s_barrier();
  RD_FRAGS(0, afE, bfE);
  asm volatile("s_waitcnt lgkmcnt(0)" ::: "memory");
  __builtin_amdgcn_s_barrier();

  const char* pAs = pA + 384;  // stage source col of tile 3
  const char* pBs = pB + 384;

  // 6-body static groups (buf period 3 x set period 2); KB=32: 4 groups
  // cover bodies 0..23, explicit tail 24..31.
#pragma unroll 1
  for (int t0 = 0; t0 < 24; t0 += 6) {
    BODY(t0 + 0, 0,     49152, afE, bfE, afO, bfO, true, true, "vmcnt(6)")
    BODY(t0 + 1, 49152, 98304, afO, bfO, afE, bfE, true, true, "vmcnt(6)")
    BODY(t0 + 2, 98304, 0,     afE, bfE, afO, bfO, true, true, "vmcnt(6)")
    BODY(t0 + 3, 0,     49152, afO, bfO, afE, bfE, true, true, "vmcnt(6)")
    BODY(t0 + 4, 49152, 98304, afE, bfE, afO, bfO, true, true, "vmcnt(6)")
    BODY(t0 + 5, 98304, 0,     afO, bfO, afE, bfE, true, true, "vmcnt(6)")
  }
  BODY(24, 0,     49152, afE, bfE, afO, bfO, true,  true,  "vmcnt(6)")
  BODY(25, 49152, 98304, afO, bfO, afE, bfE, true,  true,  "vmcnt(6)")
  BODY(26, 98304, 0,     afE, bfE, afO, bfO, true,  true,  "vmcnt(6)")
  BODY(27, 0,     49152, afO, bfO, afE, bfE, true,  true,  "vmcnt(6)")
  BODY(28, 49152, 98304, afE, bfE, afO, bfO, true,  true,  "vmcnt(6)")
  BODY(29, 98304, 0,     afO, bfO, afE, bfE, false, true,  "vmcnt(0)")
  BODY(30, 0,     49152, afE, bfE, afO, bfO, false, true,  "vmcnt(0)")
  BODY(31, 49152, 98304, afO, bfO, afE, bfE, false, false, "vmcnt(0)")

#undef BODY
#undef MFMA_ALL
#undef RD_FRAGS
#undef STG_B
#undef STG_A
#undef GL

  // epilogue (validated C/D mapping): col=l31, row=q*8+hi2*4+j
#pragma unroll
  for (int mj = 0; mj < 2; ++mj)
#pragma unroll
    for (int nj = 0; nj < 2; ++nj) {
      int col = n0 + wc * 64 + nj * 32 + l31;
#pragma unroll
      for (int q = 0; q < 4; ++q) {
        int row0 = m0 + wr * 64 + mj * 32 + q * 8 + hi2 * 4;
        f32x4 sv = *(const f32x4*)(xs + row0);
#pragma unroll
        for (int j = 0; j < 4; ++j)
          Y[(size_t)(row0 + j) * N + col] = acc[mj][nj][q * 4 + j] * sv[j];
      }
    }
}

// ---------------------------------------------------------------------------
extern "C" void kernel_launch(void* const* d_in, const int* in_sizes, int n_in,
                              void* d_out, int out_size, void* d_ws, size_t ws_size,
                              hipStream_t stream) {
  const float* x     = (const float*)d_in[0];   // [B,S,K] f32
  const float* w     = (const float*)d_in[1];   // [N,K] f32 (fp8-representable)
  const float* wsinv = (const float*)d_in[2];   // [N/128,K/128] f32
  float* y = (float*)d_out;

  const int K = 4096;
  const int M = in_sizes[0] / K;   // 4096
  const int N = in_sizes[1] / K;   // 8192

  unsigned char* x8 = (unsigned char*)d_ws;                       // M*K
  float* xs = (float*)((char*)d_ws + (size_t)M * K);              // M floats
  unsigned char* w8 =
      (unsigned char*)d_ws + (size_t)M * K + (size_t)M * 4;       // N*K

  quant_x_fp8_kernel<<<M, 256, 0, stream>>>(x, x8, xs, K);
  quant_w_fp8_kernel<<<(int)(((size_t)N * K / 16 + 255) / 256), 256, 0,
                       stream>>>(w, w8);

  dim3 grid((M / 256) * (N / 128));  // 1024
  gemm_mxfp8_kernel<<<grid, 512, 0, stream>>>(x8, w8, xs, wsinv, y, M, N, K);
}

// Round 7
// 784.974 us; speedup vs baseline: 2.1284x; 2.1284x over previous
//
#include <hip/hip_runtime.h>

typedef float f32x4  __attribute__((ext_vector_type(4)));
typedef float f32x16 __attribute__((ext_vector_type(16)));
typedef int   i32x4  __attribute__((ext_vector_type(4)));
typedef int   i32x8  __attribute__((ext_vector_type(8)));

#define AS1 __attribute__((address_space(1)))
#define AS3 __attribute__((address_space(3)))

// ---------------------------------------------------------------------------
// Kernel 1 (R1, proven): per-token quant of x -> fp8 e4m3 + scale
// ---------------------------------------------------------------------------
__global__ __launch_bounds__(256) void quant_x_fp8_kernel(
    const float* __restrict__ x, unsigned char* __restrict__ x8,
    float* __restrict__ xs, int K) {
  int m = blockIdx.x;
  int t = threadIdx.x;
  const f32x4* src = (const f32x4*)(x + (size_t)m * K + t * 16);
  f32x4 v[4];
  float am = 0.0f;
#pragma unroll
  for (int i = 0; i < 4; ++i) {
    v[i] = src[i];
#pragma unroll
    for (int j = 0; j < 4; ++j) am = fmaxf(am, __builtin_fabsf(v[i][j]));
  }
#pragma unroll
  for (int off = 32; off >= 1; off >>= 1)
    am = fmaxf(am, __shfl_xor(am, off, 64));
  __shared__ float red[4];
  int wv = t >> 6, lane = t & 63;
  if (lane == 0) red[wv] = am;
  __syncthreads();
  am = fmaxf(fmaxf(red[0], red[1]), fmaxf(red[2], red[3]));
  am = fmaxf(am, 1e-12f);
  float sc = am / 448.0f;
  if (t == 0) xs[m] = sc;
  i32x4 out;
#pragma unroll
  for (int i = 0; i < 4; ++i) {
    float q0 = v[i][0] / sc, q1 = v[i][1] / sc;
    float q2 = v[i][2] / sc, q3 = v[i][3] / sc;
    int p = __builtin_amdgcn_cvt_pk_fp8_f32(q0, q1, 0, false);
    p = __builtin_amdgcn_cvt_pk_fp8_f32(q2, q3, p, true);
    out[i] = p;
  }
  *(i32x4*)(x8 + (size_t)m * K + t * 16) = out;
}

// ---------------------------------------------------------------------------
// Kernel 2 (R1, proven): weight f32 (fp8-representable) -> fp8 bytes
// ---------------------------------------------------------------------------
__global__ __launch_bounds__(256) void quant_w_fp8_kernel(
    const float* __restrict__ w, unsigned char* __restrict__ w8) {
  size_t idx = (size_t)blockIdx.x * 256 + threadIdx.x;
  const f32x4* src = (const f32x4*)w + idx * 4;
  i32x4 out;
#pragma unroll
  for (int i = 0; i < 4; ++i) {
    f32x4 v = src[i];
    int p = __builtin_amdgcn_cvt_pk_fp8_f32(v[0], v[1], 0, false);
    p = __builtin_amdgcn_cvt_pk_fp8_f32(v[2], v[3], p, true);
    out[i] = p;
  }
  ((i32x4*)w8)[idx] = out;
}

// ---------------------------------------------------------------------------
// Kernel 3: MX-fp8 GEMM. R19 = 1024-thread 256x256 tile + ratio-fold
// C-chaining + 2-buf double buffer, 1 barrier/tile.
// R18 post-mortem: VGPR cap is HARD 128/wave for any block needing >=2
// waves/SIMD (512-reg file / SIMD; R13/R14/R18 all alloc 128 + spill).
// Register frag double-buffering is impossible. R17 audit: MfmaUtil 33% =
// 1120cy MFMA (correct), VALUBusy 28% = ~950cy VALU -- the s*t_ fold
// zero-inits + reads back a 16-reg temp per MFMA pair (~192 VALU instr).
// With only 2 phase-locked waves/SIMD, VALU+LDS+MFMA serialize.
// R19 fixes:
// (1) ratio-fold: acc kept in current-scale domain,
//     acc = mfma(a1,b1, mfma(a0,b0, acc*(s_prev/s_cur))); epilogue * s_last.
//     Telescoped factor bounded by max(s)/min(s) ~ 11 -> f32-safe. Kills
//     zero-init+readback: ~64 v_mul/wave/tile.
// (2) 1024 threads, 16 waves 4(wr)x4(wc), same 64x64/wave, acc[2][2]=64
//     VGPR (R17's proven-88 body). 4 waves/SIMD -> real cross-wave
//     LDS/VALU/MFMA overlap; staging bytes per FLOP halved.
// (3) LDS 2 bufs x 64KB {A 32KB @0, B 32KB @32768} = 131072. Stage T+1 at
//     body top (4 gloads/wave), vmcnt(0) at body end: cover ~= full body
//     (~2000cy > 900cy HBM). 1 barrier/tile.
// WAR: stage(T+1) -> buf(T-1), whose reads were drained by each wave's own
// RAW lgkm before its body-(T-1) MFMAs, and barrier(T-1) ordered them
// before this stage ✓. RAW: vmcnt(0)+barrier at body end before T+1 reads ✓.
// Swizzle (validated): 16B slot s at row r stored s^(r&7); inverse applied
// on global source (rule #21). Staging: 128-row sweeps (1024 thr x 16B =
// 16KB), A rows {rIdx, rIdx+128}, B rows {rIdx, rIdx+128} of the 256-row
// B panel.
// Scale: N-tile 256 spans 2 scale rows: wc<2 -> bn*2, else bn*2+1
// (validated R13 mapping).
// ---------------------------------------------------------------------------
__global__ __launch_bounds__(1024, 1) void gemm_mxfp8_kernel(
    const unsigned char* __restrict__ A8,   // [M][K] fp8
    const unsigned char* __restrict__ W8,   // [N][K] fp8
    const float* __restrict__ xs,           // [M]
    const float* __restrict__ wsinv,        // [N/128][K/128]
    float* __restrict__ Y,                  // [M][N] f32
    int M, int N, int K) {
  const int KB = K >> 7;  // K/128 tiles (32), even

  int bid = blockIdx.x, nwg = gridDim.x;
  int wg = (bid & 7) * (nwg >> 3) + (bid >> 3);
  int mt = M >> 8;                  // 16
  int bm = wg & (mt - 1);
  int bn = wg / mt;                 // 0..31
  int m0 = bm << 8, n0 = bn << 8;   // 256 x 256 tile

  __shared__ __align__(16) char lds[131072];  // buf0 @0, buf1 @65536

  const int tid = threadIdx.x, wv = tid >> 6, lane = tid & 63;
  const int wr = wv >> 2, wc = wv & 3;          // 4 x 4 wave grid
  const int l31 = lane & 31, hi2 = lane >> 5;
  const int salt = l31 & 7;

  // per-lane slot offsets (validated swizzle)
  const int sL0 = ((hi2 * 2 + 0) ^ salt) << 4;       // ks=0, k-low 16B
  const int sH0 = ((hi2 * 2 + 1) ^ salt) << 4;       // ks=0, k-high
  const int sL1 = ((4 + hi2 * 2 + 0) ^ salt) << 4;   // ks=1
  const int sH1 = ((4 + hi2 * 2 + 1) ^ salt) << 4;

  // per-lane anchors (buf base added as literal per body)
  const int aRow = (wr * 64 + l31) * 128;
  const int bRow = (wc * 64 + l31) * 128;
  const int aL0 = aRow + sL0, aH0 = aRow + sH0;
  const int aL1 = aRow + sL1, aH1 = aRow + sH1;
  const int bL0 = bRow + sL0, bH0 = bRow + sH0;
  const int bL1 = bRow + sL1, bH1 = bRow + sH1;

  // staging: dest = region + sweep*16384 + tid*16 (linear, 128 rows/sweep);
  // source row = sweep*128 + (tid>>3); col pre-swizzled (involution).
  const int stgD = tid << 4;
  const int rIdx = tid >> 3;                 // 0..127
  const int cSrc = ((tid & 7) ^ ((tid >> 3) & 7)) << 4;
  const size_t rowB = (size_t)K;  // fp8: 1 byte/elem
  const size_t g128 = 128 * rowB;
  const char* pA = (const char*)A8 + (size_t)(m0 + rIdx) * rowB + cSrc;
  const char* pB = (const char*)W8 + (size_t)(n0 + rIdx) * rowB + cSrc;

  // scale row: wc 0,1 -> bn*2 (cols 0-127), wc 2,3 -> bn*2+1 (cols 128-255)
  const float* wsv = wsinv + (size_t)(bn * 2 + (wc >> 1)) * KB;

  f32x16 acc[2][2];
#pragma unroll
  for (int i = 0; i < 2; ++i)
#pragma unroll
    for (int j = 0; j < 2; ++j) acc[i][j] = (f32x16)0.0f;

  i32x8 af[2], bf[2][2];

#define GL(SRC, DST)                                                           \
  __builtin_amdgcn_global_load_lds((const AS1 void*)(SRC), (AS3 void*)(DST),   \
                                   16, 0, 0)
// 256-row panel (32KB) in 2 sweeps of 128 rows
#define STG(COND, SB, SRC)                                                     \
  if (COND) {                                                                  \
    const char* s_ = (SRC);                                                    \
    char* d_ = lds + (SB) + stgD;                                              \
    GL(s_, d_);                                                                \
    GL(s_ + g128, d_ + 16384);                                                 \
  }

// A frags for one mj (both ksteps) from buf base BR: 4 ds_read_b128
#define RD_A(BR, MJ)                                                           \
  {                                                                            \
    const char* p_ = lds + (BR) + (MJ) * 4096;                                 \
    i32x4 lo0 = *(const i32x4*)(p_ + aL0);                                     \
    i32x4 hi0 = *(const i32x4*)(p_ + aH0);                                     \
    i32x4 lo1 = *(const i32x4*)(p_ + aL1);                                     \
    i32x4 hi1 = *(const i32x4*)(p_ + aH1);                                     \
    af[0] = __builtin_shufflevector(lo0, hi0, 0, 1, 2, 3, 4, 5, 6, 7);         \
    af[1] = __builtin_shufflevector(lo1, hi1, 0, 1, 2, 3, 4, 5, 6, 7);         \
  }
// all B frags (nj 0..1 x ks 0..1) from buf base BR (B region +32768)
#define RD_B(BR)                                                               \
  _Pragma("unroll") for (int nj = 0; nj < 2; ++nj) {                           \
    const char* p_ = lds + (BR) + 32768 + nj * 4096;                           \
    i32x4 lo0 = *(const i32x4*)(p_ + bL0);                                     \
    i32x4 hi0 = *(const i32x4*)(p_ + bH0);                                     \
    i32x4 lo1 = *(const i32x4*)(p_ + bL1);                                     \
    i32x4 hi1 = *(const i32x4*)(p_ + bH1);                                     \
    bf[nj][0] = __builtin_shufflevector(lo0, hi0, 0, 1, 2, 3, 4, 5, 6, 7);     \
    bf[nj][1] = __builtin_shufflevector(lo1, hi1, 0, 1, 2, 3, 4, 5, 6, 7);     \
  }

// ratio-fold + 4 MFMA for one mj: acc = mfma(a1,b1, mfma(a0,b0, acc*R))
#define MMF(MJ, R_)                                                            \
  _Pragma("unroll") for (int nj = 0; nj < 2; ++nj) {                           \
    f32x16 c_;                                                                 \
    _Pragma("unroll") for (int q = 0; q < 16; ++q)                             \
        c_[q] = acc[MJ][nj][q] * (R_);                                         \
    c_ = __builtin_amdgcn_mfma_scale_f32_32x32x64_f8f6f4(                      \
        af[0], bf[nj][0], c_, 0, 0, 0, 0x7f7f7f7f, 0, 0x7f7f7f7f);             \
    acc[MJ][nj] = __builtin_amdgcn_mfma_scale_f32_32x32x64_f8f6f4(             \
        af[1], bf[nj][1], c_, 0, 0, 0, 0x7f7f7f7f, 0, 0x7f7f7f7f);             \
  }

// body T: stage T+1 -> BS; read+MFMA tile T from BR; vmcnt drain; barrier.
#define BODY(T, BR, BS, G)                                                     \
  {                                                                            \
    float sc_ = wsv[(T)];                                                      \
    float r_ = sp_ / sc_;                                                      \
    RD_B(BR);                                                                  \
    RD_A(BR, 0);                                                               \
    STG(G, (BS), pAs);                                                         \
    STG(G, (BS) + 32768, pBs);                                                 \
    __builtin_amdgcn_s_setprio(1);                                             \
    MMF(0, r_);                                                                \
    __builtin_amdgcn_s_setprio(0);                                             \
    RD_A(BR, 1);                                                               \
    __builtin_amdgcn_s_setprio(1);                                             \
    MMF(1, r_);                                                                \
    __builtin_amdgcn_s_setprio(0);                                             \
    sp_ = sc_;                                                                 \
    asm volatile("s_waitcnt vmcnt(0)" ::: "memory");                           \
    __builtin_amdgcn_s_barrier();                                              \
    pAs += 128;                                                                \
    pBs += 128;                                                                \
  }

  // prologue: stage tile0 -> buf0 (4 gloads/thread); drain; publish.
  STG(true, 0, pA);
  STG(true, 32768, pB);
  asm volatile("s_waitcnt vmcnt(0)" ::: "memory");
  __builtin_amdgcn_s_barrier();

  const char* pAs = pA + 128;  // stage source col of tile 1
  const char* pBs = pB + 128;
  float sp_ = wsv[0];          // previous-tile scale (ratio=1 at t=0)

#pragma unroll 1
  for (int t = 0; t < KB; t += 2) {
    BODY(t,     0,     65536, true)
    BODY(t + 1, 65536, 0,     (t + 2) < KB)
  }

#undef BODY
#undef MMF
#undef RD_B
#undef RD_A
#undef STG
#undef GL

  // epilogue (validated C/D mapping): col=l31, row=q*8+hi2*4+j;
  // undo scale domain: * s_last (= sp_ after loop) folded into xs.
  const float sl_ = sp_;
#pragma unroll
  for (int mj = 0; mj < 2; ++mj)
#pragma unroll
    for (int nj = 0; nj < 2; ++nj) {
      int col = n0 + wc * 64 + nj * 32 + l31;
#pragma unroll
      for (int q = 0; q < 4; ++q) {
        int row0 = m0 + wr * 64 + mj * 32 + q * 8 + hi2 * 4;
        f32x4 sv = *(const f32x4*)(xs + row0);
#pragma unroll
        for (int j = 0; j < 4; ++j)
          Y[(size_t)(row0 + j) * N + col] = acc[mj][nj][q * 4 + j] * sv[j] * sl_;
      }
    }
}

// ---------------------------------------------------------------------------
extern "C" void kernel_launch(void* const* d_in, const int* in_sizes, int n_in,
                              void* d_out, int out_size, void* d_ws, size_t ws_size,
                              hipStream_t stream) {
  const float* x     = (const float*)d_in[0];   // [B,S,K] f32
  const float* w     = (const float*)d_in[1];   // [N,K] f32 (fp8-representable)
  const float* wsinv = (const float*)d_in[2];   // [N/128,K/128] f32
  float* y = (float*)d_out;

  const int K = 4096;
  const int M = in_sizes[0] / K;   // 4096
  const int N = in_sizes[1] / K;   // 8192

  unsigned char* x8 = (unsigned char*)d_ws;                       // M*K
  float* xs = (float*)((char*)d_ws + (size_t)M * K);              // M floats
  unsigned char* w8 =
      (unsigned char*)d_ws + (size_t)M * K + (size_t)M * 4;       // N*K

  quant_x_fp8_kernel<<<M, 256, 0, stream>>>(x, x8, xs, K);
  quant_w_fp8_kernel<<<(int)(((size_t)N * K / 16 + 255) / 256), 256, 0,
                       stream>>>(w, w8);

  dim3 grid((M / 256) * (N / 256));  // 512
  gemm_mxfp8_kernel<<<grid, 1024, 0, stream>>>(x8, w8, xs, wsinv, y, M, N, K);
}

// Round 8
// 226.654 us; speedup vs baseline: 7.3712x; 3.4633x over previous
//
#include <hip/hip_runtime.h>

typedef float f32x4  __attribute__((ext_vector_type(4)));
typedef float f32x16 __attribute__((ext_vector_type(16)));
typedef int   i32x4  __attribute__((ext_vector_type(4)));
typedef int   i32x8  __attribute__((ext_vector_type(8)));

#define AS1 __attribute__((address_space(1)))
#define AS3 __attribute__((address_space(3)))

// ---------------------------------------------------------------------------
// Kernel 1 (R1, proven): per-token quant of x -> fp8 e4m3 + scale
// ---------------------------------------------------------------------------
__global__ __launch_bounds__(256) void quant_x_fp8_kernel(
    const float* __restrict__ x, unsigned char* __restrict__ x8,
    float* __restrict__ xs, int K) {
  int m = blockIdx.x;
  int t = threadIdx.x;
  const f32x4* src = (const f32x4*)(x + (size_t)m * K + t * 16);
  f32x4 v[4];
  float am = 0.0f;
#pragma unroll
  for (int i = 0; i < 4; ++i) {
    v[i] = src[i];
#pragma unroll
    for (int j = 0; j < 4; ++j) am = fmaxf(am, __builtin_fabsf(v[i][j]));
  }
#pragma unroll
  for (int off = 32; off >= 1; off >>= 1)
    am = fmaxf(am, __shfl_xor(am, off, 64));
  __shared__ float red[4];
  int wv = t >> 6, lane = t & 63;
  if (lane == 0) red[wv] = am;
  __syncthreads();
  am = fmaxf(fmaxf(red[0], red[1]), fmaxf(red[2], red[3]));
  am = fmaxf(am, 1e-12f);
  float sc = am / 448.0f;
  if (t == 0) xs[m] = sc;
  i32x4 out;
#pragma unroll
  for (int i = 0; i < 4; ++i) {
    float q0 = v[i][0] / sc, q1 = v[i][1] / sc;
    float q2 = v[i][2] / sc, q3 = v[i][3] / sc;
    int p = __builtin_amdgcn_cvt_pk_fp8_f32(q0, q1, 0, false);
    p = __builtin_amdgcn_cvt_pk_fp8_f32(q2, q3, p, true);
    out[i] = p;
  }
  *(i32x4*)(x8 + (size_t)m * K + t * 16) = out;
}

// ---------------------------------------------------------------------------
// Kernel 2 (R1, proven): weight f32 (fp8-representable) -> fp8 bytes
// ---------------------------------------------------------------------------
__global__ __launch_bounds__(256) void quant_w_fp8_kernel(
    const float* __restrict__ w, unsigned char* __restrict__ w8) {
  size_t idx = (size_t)blockIdx.x * 256 + threadIdx.x;
  const f32x4* src = (const f32x4*)w + idx * 4;
  i32x4 out;
#pragma unroll
  for (int i = 0; i < 4; ++i) {
    f32x4 v = src[i];
    int p = __builtin_amdgcn_cvt_pk_fp8_f32(v[0], v[1], 0, false);
    p = __builtin_amdgcn_cvt_pk_fp8_f32(v[2], v[3], p, true);
    out[i] = p;
  }
  ((i32x4*)w8)[idx] = out;
}

// ---------------------------------------------------------------------------
// Kernel 3: MX-fp8 GEMM. R20 = R17 structure + ratio-fold C-chaining.
// R19 post-mortem: 1024-thread blocks -> allocator budgets 64 VGPR/wave ->
// massive spill (WRITE 1.84GB). Discarded. R17 audit: 3400cy/body =
// LDS 1900 + MFMA 1100 + VALU 950 nearly SERIAL; biggest removable term is
// the fold VALU (~190 instr/wave/tile: t_ zero-init + MFMA->VALU readback
// + 64 fmaf). SQ_LDS_BANK_CONFLICT == 2^24 in every round -> artifact.
// R20: keep acc in current-tile scale domain:
//   acc *= (s_{t-1}/s_t)  (16 in-place muls, only VALU touch)
//   acc = mfma(a1,b1, mfma(a0,b0, acc))   (direct C-chain, no temp)
// Epilogue * s_last. Numerics VALIDATED by R19 (passed, absmax 0.0625;
// telescoped factor bounded by max(s)/min(s) ~ 11). Register pressure
// strictly drops vs R17's proven 88 (t_ tuple gone). Body re-chunked
// per (mj,nj): first MFMA waits on 8 ds_reads not 12.
// Geometry (R12/R17-proven): block 256(M)x128(N), K-tile 128, 8 waves
// 4(wr)x2(wc), wave 64x64 -> acc[2][2] f32x16.
// LDS: A0@0 A1@32768 A2@65536; B0@98304 B1@114688 B2@131072 (147456).
// 1 barrier/tile (R17): with 3-deep A and B, stage(T+2) overwrites the
// buf of T-1 whose last read preceded the tile-T barrier -> race-free.
// vmcnt ledger (R17): end of body T outstanding = STG(T+1) 6 + STG(T+2) 6
// = 12; vmcnt(6) retires all of T+1 before its publish barrier.
// Tail (KB-2, KB-1): no staging; vmcnt(0).
// Swizzle (validated): 16B slot s at row r stored s^(r&7); inverse applied
// on global source (rule #21).
// ---------------------------------------------------------------------------
__global__ __launch_bounds__(512, 1) void gemm_mxfp8_kernel(
    const unsigned char* __restrict__ A8,   // [M][K] fp8
    const unsigned char* __restrict__ W8,   // [N][K] fp8
    const float* __restrict__ xs,           // [M]
    const float* __restrict__ wsinv,        // [N/128][K/128]
    float* __restrict__ Y,                  // [M][N] f32
    int M, int N, int K) {
  const int KB = K >> 7;  // K/128 tiles (32)

  int bid = blockIdx.x, nwg = gridDim.x;
  int wg = (bid & 7) * (nwg >> 3) + (bid >> 3);
  int mt = M >> 8;                  // 16
  int bm = wg & (mt - 1);
  int bn = wg / mt;
  int m0 = bm << 8, n0 = bn << 7;   // 256 x 128 tile

  __shared__ __align__(16) char lds[147456];

  const int tid = threadIdx.x, wv = tid >> 6, lane = tid & 63;
  const int wr = wv >> 1, wc = wv & 1;          // 4 x 2 wave grid
  const int l31 = lane & 31, hi2 = lane >> 5;
  const int salt = l31 & 7;

  // per-lane slot offsets (validated swizzle)
  const int sL0 = ((hi2 * 2 + 0) ^ salt) << 4;       // ks=0, k-low 16B
  const int sH0 = ((hi2 * 2 + 1) ^ salt) << 4;       // ks=0, k-high
  const int sL1 = ((4 + hi2 * 2 + 0) ^ salt) << 4;   // ks=1
  const int sH1 = ((4 + hi2 * 2 + 1) ^ salt) << 4;

  // shared per-lane anchors (region base added at runtime)
  const int aRow = (wr * 64 + l31) * 128;
  const int bRow = (wc * 64 + l31) * 128;
  const int aL0 = aRow + sL0, aH0 = aRow + sH0;
  const int aL1 = aRow + sL1, aH1 = aRow + sH1;
  const int bL0 = bRow + sL0, bH0 = bRow + sH0;
  const int bL1 = bRow + sL1, bH1 = bRow + sH1;

  // staging: dest = region + sweep*8192 + tid*16 (linear, 64 rows/sweep);
  // source row = sweep*64 + (tid>>3); col pre-swizzled (involution).
  const int stgD = tid << 4;
  const int rIdx = tid >> 3;
  const int cSrc = ((tid & 7) ^ ((tid >> 3) & 7)) << 4;
  const size_t rowB = (size_t)K;  // fp8: 1 byte/elem
  const size_t g64 = 64 * rowB;
  const char* pA = (const char*)A8 + (size_t)(m0 + rIdx) * rowB + cSrc;
  const char* pB = (const char*)W8 + (size_t)(n0 + rIdx) * rowB + cSrc;

  const float* wsv = wsinv + (size_t)bn * KB;  // block-uniform scale row

  f32x16 acc[2][2];
#pragma unroll
  for (int i = 0; i < 2; ++i)
#pragma unroll
    for (int j = 0; j < 2; ++j) acc[i][j] = (f32x16)0.0f;

  i32x8 af[2], bf[2][2];

#define GL(SRC, DST)                                                           \
  __builtin_amdgcn_global_load_lds((const AS1 void*)(SRC), (AS3 void*)(DST),   \
                                   16, 0, 0)
#define STG_A(COND, SB, SRC)                                                   \
  if (COND) {                                                                  \
    const char* s_ = (SRC);                                                    \
    char* d_ = lds + (SB) + stgD;                                              \
    GL(s_, d_);                                                                \
    GL(s_ + g64, d_ + 8192);                                                   \
    GL(s_ + 2 * g64, d_ + 16384);                                              \
    GL(s_ + 3 * g64, d_ + 24576);                                              \
  }
#define STG_B(COND, SB, SRC)                                                   \
  if (COND) {                                                                  \
    const char* s_ = (SRC);                                                    \
    char* d_ = lds + (SB) + stgD;                                              \
    GL(s_, d_);                                                                \
    GL(s_ + g64, d_ + 8192);                                                   \
  }

// A frags for one mj (both ksteps), runtime region base RB: 4 ds_read_b128
#define RD_A(RB, MJ)                                                           \
  {                                                                            \
    const char* p_ = lds + (RB) + (MJ) * 4096;                                 \
    i32x4 lo0 = *(const i32x4*)(p_ + aL0);                                     \
    i32x4 hi0 = *(const i32x4*)(p_ + aH0);                                     \
    i32x4 lo1 = *(const i32x4*)(p_ + aL1);                                     \
    i32x4 hi1 = *(const i32x4*)(p_ + aH1);                                     \
    af[0] = __builtin_shufflevector(lo0, hi0, 0, 1, 2, 3, 4, 5, 6, 7);         \
    af[1] = __builtin_shufflevector(lo1, hi1, 0, 1, 2, 3, 4, 5, 6, 7);         \
  }
// B frags for ONE nj (both ksteps), runtime region base RB: 4 ds_read_b128
#define RD_Bn(RB, NJ)                                                          \
  {                                                                            \
    const char* p_ = lds + (RB) + (NJ) * 4096;                                 \
    i32x4 lo0 = *(const i32x4*)(p_ + bL0);                                     \
    i32x4 hi0 = *(const i32x4*)(p_ + bH0);                                     \
    i32x4 lo1 = *(const i32x4*)(p_ + bL1);                                     \
    i32x4 hi1 = *(const i32x4*)(p_ + bH1);                                     \
    bf[NJ][0] = __builtin_shufflevector(lo0, hi0, 0, 1, 2, 3, 4, 5, 6, 7);     \
    bf[NJ][1] = __builtin_shufflevector(lo1, hi1, 0, 1, 2, 3, 4, 5, 6, 7);     \
  }

// ratio-fold + chained MFMA pair for one (mj,nj); acc touched only by the
// in-place mul and as MFMA C/D.
#define MMFn(MJ, NJ, R_)                                                       \
  {                                                                            \
    _Pragma("unroll") for (int q = 0; q < 16; ++q)                             \
        acc[MJ][NJ][q] *= (R_);                                                \
    acc[MJ][NJ] = __builtin_amdgcn_mfma_scale_f32_32x32x64_f8f6f4(             \
        af[0], bf[NJ][0], acc[MJ][NJ], 0, 0, 0, 0x7f7f7f7f, 0, 0x7f7f7f7f);    \
    acc[MJ][NJ] = __builtin_amdgcn_mfma_scale_f32_32x32x64_f8f6f4(             \
        af[1], bf[NJ][1], acc[MJ][NJ], 0, 0, 0, 0x7f7f7f7f, 0, 0x7f7f7f7f);    \
  }

  // prologue: A(0)->A0, B(0)->B0, A(1)->A1, B(1)->B1 (12 gloads);
  // vmcnt(6) completes tile0's 6, leaves tile1's 6 = steady invariant.
  STG_A(true, 0, pA);
  STG_B(true, 98304, pB);
  STG_A(true, 32768, pA + 128);
  STG_B(true, 114688, pB + 128);
  asm volatile("s_waitcnt vmcnt(6)" ::: "memory");
  __builtin_amdgcn_s_barrier();

  // rotating region bases (wave-uniform scalars) + rolling stage sources
  int rdA = 0;           // A-buf of tile T: {0,32768,65536} cycle
  int stA = 65536;       // A-buf of tile T+2
  int rdB = 98304;       // B-buf of tile T: {98304,114688,131072} cycle
  int stB = 131072;      // B-buf of tile T+2
  const char* pAs = pA + 256;  // A source col of tile T+2
  const char* pBs = pB + 256;
  float sp_ = wsv[0];    // previous-tile scale (ratio = 1 at t = 0)

#define TILE(T, G, VM)                                                         \
  {                                                                            \
    float sc_ = wsv[(T)];                                                      \
    float r_ = sp_ / sc_;                                                      \
    RD_A(rdA, 0);                                                              \
    RD_Bn(rdB, 0);                                                             \
    __builtin_amdgcn_s_setprio(1);                                             \
    MMFn(0, 0, r_);                                                            \
    __builtin_amdgcn_s_setprio(0);                                             \
    STG_A(G, stA, pAs);                                                        \
    STG_B(G, stB, pBs);                                                        \
    RD_Bn(rdB, 1);                                                             \
    __builtin_amdgcn_s_setprio(1);                                             \
    MMFn(0, 1, r_);                                                            \
    __builtin_amdgcn_s_setprio(0);                                             \
    RD_A(rdA, 1);                                                              \
    __builtin_amdgcn_s_setprio(1);                                             \
    MMFn(1, 0, r_);                                                            \
    MMFn(1, 1, r_);                                                            \
    __builtin_amdgcn_s_setprio(0);                                             \
    sp_ = sc_;                                                                 \
    asm volatile("s_waitcnt " VM ::: "memory");                                \
    __builtin_amdgcn_s_barrier();                                              \
    rdA = (rdA == 65536) ? 0 : rdA + 32768;                                    \
    stA = (stA == 65536) ? 0 : stA + 32768;                                    \
    rdB = (rdB == 131072) ? 98304 : rdB + 16384;                               \
    stB = (stB == 131072) ? 98304 : stB + 16384;                               \
    pAs += 128;                                                                \
    pBs += 128;                                                                \
  }

#pragma unroll 1
  for (int t = 0; t < KB - 2; ++t) {
    TILE(t, true, "vmcnt(6)")
  }
  // tail: tiles KB-2, KB-1; no staging; drain before last reads.
  TILE(KB - 2, false, "vmcnt(0)")
  TILE(KB - 1, false, "vmcnt(0)")

#undef TILE
#undef MMFn
#undef RD_Bn
#undef RD_A
#undef STG_B
#undef STG_A
#undef GL

  // epilogue (validated C/D mapping): col=l31, row=q*8+hi2*4+j.
  // acc is in s_last domain: Y = acc * s_last * xs[row].
  const float sl_ = sp_;
#pragma unroll
  for (int mj = 0; mj < 2; ++mj)
#pragma unroll
    for (int nj = 0; nj < 2; ++nj) {
      int col = n0 + wc * 64 + nj * 32 + l31;
#pragma unroll
      for (int q = 0; q < 4; ++q) {
        int row0 = m0 + wr * 64 + mj * 32 + q * 8 + hi2 * 4;
        f32x4 sv = *(const f32x4*)(xs + row0);
#pragma unroll
        for (int j = 0; j < 4; ++j)
          Y[(size_t)(row0 + j) * N + col] = acc[mj][nj][q * 4 + j] * sv[j] * sl_;
      }
    }
}

// ---------------------------------------------------------------------------
extern "C" void kernel_launch(void* const* d_in, const int* in_sizes, int n_in,
                              void* d_out, int out_size, void* d_ws, size_t ws_size,
                              hipStream_t stream) {
  const float* x     = (const float*)d_in[0];   // [B,S,K] f32
  const float* w     = (const float*)d_in[1];   // [N,K] f32 (fp8-representable)
  const float* wsinv = (const float*)d_in[2];   // [N/128,K/128] f32
  float* y = (float*)d_out;

  const int K = 4096;
  const int M = in_sizes[0] / K;   // 4096
  const int N = in_sizes[1] / K;   // 8192

  unsigned char* x8 = (unsigned char*)d_ws;                       // M*K
  float* xs = (float*)((char*)d_ws + (size_t)M * K);              // M floats
  unsigned char* w8 =
      (unsigned char*)d_ws + (size_t)M * K + (size_t)M * 4;       // N*K

  quant_x_fp8_kernel<<<M, 256, 0, stream>>>(x, x8, xs, K);
  quant_w_fp8_kernel<<<(int)(((size_t)N * K / 16 + 255) / 256), 256, 0,
                       stream>>>(w, w8);

  dim3 grid((M / 256) * (N / 128));  // 1024
  gemm_mxfp8_kernel<<<grid, 512, 0, stream>>>(x8, w8, xs, wsinv, y, M, N, K);
}